// Round 7
// baseline (323.704 us; speedup 1.0000x reference)
//
#include <hip/hip_runtime.h>
#include <math.h>

// Problem constants
#define BATCH   8192
#define IN_DIM  1024
#define LAT     256
#define NEMB    8192

// flag margin; score err sigma ~3.2e-4 (fp16 rounding of BOTH z-hi and e-hat),
// TAU ~ 10 sigma. Flagged rows get exact fp32 rescore.
#define TAU 3.5e-3f

// rescore row-parallelism (grid.y); blocks stride the flag list by 2*RESC_R
#define RESC_R 16

// scorer column splits (grid.x); each handles NEMB/CSPLIT codes
#define CSPLIT 16

typedef _Float16 f16x8 __attribute__((ext_vector_type(8)));
typedef _Float16 f16x4 __attribute__((ext_vector_type(4)));
typedef float f32x16_t __attribute__((ext_vector_type(16)));

typedef __attribute__((address_space(1))) const unsigned int gu32_t;
typedef __attribute__((address_space(3))) unsigned int lu32_t;

// order-preserving float<->u32 transform
__device__ __forceinline__ unsigned int ford(float x) {
  unsigned int u = __float_as_uint(x);
  return (u & 0x80000000u) ? ~u : (u | 0x80000000u);
}
__device__ __forceinline__ float funord(unsigned int t) {
  unsigned int u = (t & 0x80000000u) ? (t & 0x7FFFFFFFu) : ~t;
  return __uint_as_float(u);
}

// ---------------------------------------------------------------------------
// Per-code inverse norms: one wave per embedding row.
// ---------------------------------------------------------------------------
__global__ __launch_bounds__(256) void emb_norms(
    const float* __restrict__ emb, float* __restrict__ inv_norm) {
  int row = blockIdx.x * 4 + (threadIdx.x >> 6);
  int lane = threadIdx.x & 63;
  const float* p = emb + (size_t)row * LAT;
  float s = 0.f;
#pragma unroll
  for (int t = 0; t < 4; ++t) {
    float v = p[lane + 64 * t];
    s += v * v;
  }
#pragma unroll
  for (int off = 32; off; off >>= 1) s += __shfl_xor(s, off);
  if (lane == 0) inv_norm[row] = 1.0f / sqrtf(s);
}

// ---------------------------------------------------------------------------
// Split fp32 [R x K] (optionally scaled per-row) into fp16 hi (+ optional lo)
// in MFMA-32x32x16 fragment order:
//   frag block g=(tile,kb): lane l -> elem [tile*32+(l&31)][kb*16+(l>>5)*8+j]
//   stored at dst[(g*64+l)*8 + j]; lo at dst + lo_off (= R*K) if write_lo.
// ---------------------------------------------------------------------------
__global__ __launch_bounds__(256) void split16(
    const float* __restrict__ src, const float* __restrict__ inv_norm,
    _Float16* __restrict__ dst, size_t lo_off, int KD, int write_lo) {
  int gw = (blockIdx.x * 256 + threadIdx.x) >> 6;
  int l = threadIdx.x & 63;
  int tile = gw / KD, kb = gw % KD;
  int row = tile * 32 + (l & 31);
  int k = kb * 16 + (l >> 5) * 8;
  const float* p = src + (size_t)row * (KD * 16) + k;
  float scale = inv_norm ? inv_norm[row] : 1.0f;
  f16x8 h, lo;
#pragma unroll
  for (int j = 0; j < 8; ++j) {
    float v = p[j] * scale;
    _Float16 hh = (_Float16)v;
    h[j] = hh;
    lo[j] = (_Float16)(v - (float)hh);
  }
  size_t o = ((size_t)gw * 64 + l) * 8;
  *(f16x8*)(dst + o) = h;
  if (write_lo) *(f16x8*)(dst + lo_off + o) = lo;
}

// ---------------------------------------------------------------------------
// Split-fp16 MFMA GEMM, BOTH operands pre-split in fragment order.
// C[M][N] = A@B^T + bias. Block 64x64, 4 waves (mt=w&1, nt=w>>1), K-slice 64.
// All staging via global_load_lds width=16. 3 MFMAs per k-step.
// ---------------------------------------------------------------------------
__global__ __launch_bounds__(256) void gemm16_frag(
    const _Float16* __restrict__ Afrag, size_t a_lo_off,
    const _Float16* __restrict__ Bfrag, size_t b_lo_off,
    const float* __restrict__ bias, float* __restrict__ C, int N, int K) {
  __shared__ char lds[32768];  // A chunks [0,16K): (mt*8+prec*4+ks); B at 16K
  const int tid = threadIdx.x;
  const int l = tid & 63;
  const int w = tid >> 6;
  const int mt = w & 1, nt = w >> 1;
  const int rb = blockIdx.y * 64, cb = blockIdx.x * 64;
  const int KD = K >> 4;

  f32x16_t acc = (f32x16_t)0.0f;

  for (int s = 0; s < (K >> 6); ++s) {
#pragma unroll
    for (int i = 0; i < 8; ++i) {
      int c = i * 4 + w;  // 0..31
      int isB = c >> 4;
      int cc = c & 15;
      int t32 = cc >> 3, prec = (cc >> 2) & 1, ks = cc & 3;
      int tile = ((isB ? cb : rb) >> 5) + t32;
      int kb = s * 4 + ks;
      const _Float16* base = isB ? Bfrag : Afrag;
      size_t lo = isB ? b_lo_off : a_lo_off;
      const _Float16* src =
          base + (size_t)prec * lo + ((size_t)(tile * KD + kb) * 64 + l) * 8;
      __builtin_amdgcn_global_load_lds((gu32_t*)src,
                                       (lu32_t*)(lds + (c << 10) + l * 16),
                                       16, 0, 0);
    }
    __syncthreads();
#pragma unroll
    for (int ks = 0; ks < 4; ++ks) {
      f16x8 ah = *(const f16x8*)(lds + ((mt * 8 + ks) << 10) + l * 16);
      f16x8 al = *(const f16x8*)(lds + ((mt * 8 + 4 + ks) << 10) + l * 16);
      f16x8 bh = *(const f16x8*)(lds + 16384 + ((nt * 8 + ks) << 10) + l * 16);
      f16x8 bl = *(const f16x8*)(lds + 16384 + ((nt * 8 + 4 + ks) << 10) + l * 16);
      acc = __builtin_amdgcn_mfma_f32_32x32x16_f16(ah, bh, acc, 0, 0, 0);
      acc = __builtin_amdgcn_mfma_f32_32x32x16_f16(ah, bl, acc, 0, 0, 0);
      acc = __builtin_amdgcn_mfma_f32_32x32x16_f16(al, bh, acc, 0, 0, 0);
    }
    __syncthreads();
  }

  int col = cb + nt * 32 + (l & 31);
  float bv = bias[col];
#pragma unroll
  for (int r = 0; r < 16; ++r) {
    int row = rb + mt * 32 + (r & 3) + 8 * (r >> 2) + 4 * (l >> 5);
    C[(size_t)row * N + col] = acc[r] + bv;
  }
}

// ---------------------------------------------------------------------------
// Fallback GEMM (A fp32, split to fp16 hi/lo in-kernel): as round 3.
// ---------------------------------------------------------------------------
__global__ __launch_bounds__(256) void gemm16(
    const float* __restrict__ A, const _Float16* __restrict__ Bfrag,
    size_t b_lo_off, const float* __restrict__ bias, float* __restrict__ C,
    int M, int N, int K) {
  __shared__ char lds[32768];
  const int tid = threadIdx.x;
  const int l = tid & 63;
  const int w = tid >> 6;
  const int mt = w & 1, nt = w >> 1;
  const int rb = blockIdx.y * 64, cb = blockIdx.x * 64;
  const int KD = K >> 4;

  f32x16_t acc = (f32x16_t)0.0f;

  for (int s = 0; s < (K >> 6); ++s) {
#pragma unroll
    for (int i = 0; i < 4; ++i) {
      int c = i * 4 + w;  // 0..15: ((bnt*2+prec)*4+ks)
      int bnt = c >> 3, prec = (c >> 2) & 1, ks = c & 3;
      int tile = (cb >> 5) + bnt, ksg = s * 4 + ks;
      const _Float16* src = Bfrag + (size_t)prec * b_lo_off +
                            ((size_t)(tile * KD + ksg) * 64 + l) * 8;
      __builtin_amdgcn_global_load_lds((gu32_t*)src,
                                       (lu32_t*)(lds + 16384 + (c << 10) + l * 16),
                                       16, 0, 0);
    }
#pragma unroll
    for (int t = 0; t < 4; ++t) {
      int flat = t * 256 + tid;
      int r = flat >> 4, c4 = flat & 15;
      float4 v = *(const float4*)&A[(size_t)(rb + r) * K + s * 64 + 4 * c4];
      int kk = 4 * c4;
      int ks = kk >> 4, j = kk & 7;
      int lane2 = (r & 31) + 32 * ((kk >> 3) & 1);
      int mtt = r >> 5;
      f16x4 hv, lv;
      float vv[4] = {v.x, v.y, v.z, v.w};
#pragma unroll
      for (int e = 0; e < 4; ++e) {
        _Float16 h = (_Float16)vv[e];
        hv[e] = h;
        lv[e] = (_Float16)(vv[e] - (float)h);
      }
      int base = ((mtt * 8 + ks) << 10) + lane2 * 16 + j * 2;
      *(f16x4*)(lds + base) = hv;
      *(f16x4*)(lds + base + 4096) = lv;
    }
    __syncthreads();
#pragma unroll
    for (int ks = 0; ks < 4; ++ks) {
      f16x8 ah = *(const f16x8*)(lds + ((mt * 8 + ks) << 10) + l * 16);
      f16x8 al = *(const f16x8*)(lds + ((mt * 8 + 4 + ks) << 10) + l * 16);
      f16x8 bh = *(const f16x8*)(lds + 16384 + ((nt * 8 + ks) << 10) + l * 16);
      f16x8 bl = *(const f16x8*)(lds + 16384 + ((nt * 8 + 4 + ks) << 10) + l * 16);
      acc = __builtin_amdgcn_mfma_f32_32x32x16_f16(ah, bh, acc, 0, 0, 0);
      acc = __builtin_amdgcn_mfma_f32_32x32x16_f16(ah, bl, acc, 0, 0, 0);
      acc = __builtin_amdgcn_mfma_f32_32x32x16_f16(al, bh, acc, 0, 0, 0);
    }
    __syncthreads();
  }

  int col = cb + nt * 32 + (l & 31);
  float bv = bias[col];
#pragma unroll
  for (int r = 0; r < 16; ++r) {
    int row = rb + mt * 32 + (r & 3) + 8 * (r >> 2) + 4 * (l >> 5);
    C[(size_t)row * N + col] = acc[r] + bv;
  }
}

// ---------------------------------------------------------------------------
// Scorer v7: NO LDS, NO BARRIERS. B fragments load DIRECTLY from global
// (L2-resident 256 KB per csplit; fragment order -> each lane's 16B operand
// is one coalesced global_load_dwordx4). Waves fully independent; compiler
// software-pipelines the load->MFMA stream across tiles with counted
// waitcnts (its strength) instead of our barrier-drained LDS pipeline.
// v2-v6 evidence: the LDS staging + barrier structure capped residency/
// overlap at ~20% MfmaUtil regardless of barrier count, chain splitting,
// grid size, or VGPR -- so remove the structure.
//   - A (z): full K in registers per wave (16 x f16x8 = 64 VGPR), loaded once.
//   - Per tile t (32 cols): 16 x {global_load_dwordx4 B-frag -> MFMA}, single
//     acc chain (dual bought nothing in v6), branchless med3 top-2 merge.
//   - Grid (CSPLIT=16, 64): 1024 blocks; residency VGPR-limited only.
// ---------------------------------------------------------------------------
__global__ __launch_bounds__(256) void score_mfma(
    const _Float16* __restrict__ zfrag, const _Float16* __restrict__ efrag,
    unsigned long long* __restrict__ cand1, unsigned int* __restrict__ cand2) {
  const int tid = threadIdx.x;
  const int l = tid & 63;
  const int w = tid >> 6;
  const int csplit = blockIdx.x;  // 0..15
  const int rowgrp = blockIdx.y;  // 0..63

  // ---- A: this wave's 32 rows, full K=256, hi-only, in registers ----
  f16x8 a[16];
  {
    const _Float16* ab =
        zfrag + (((size_t)(rowgrp * 4 + w) * 16) * 64 + l) * 8;
#pragma unroll
    for (int kf = 0; kf < 16; ++kf)
      a[kf] = *(const f16x8*)(ab + (size_t)kf * 512);
  }

  float b1[16], b2[16];
  int i1[16];
#pragma unroll
  for (int r = 0; r < 16; ++r) {
    b1[r] = -INFINITY;
    b2[r] = -INFINITY;
    i1[r] = 0;
  }

  // efrag (elements): csplit slice = 131072; tile stride 8192; frag stride
  // 512; lane offset l*8. Each f16x8 read = coalesced 1KB per wave.
  const _Float16* eb = efrag + (size_t)csplit * 131072 + (size_t)l * 8;

#pragma unroll 1
  for (int t = 0; t < 16; ++t) {
    const _Float16* bt = eb + (size_t)t * 8192;
    f32x16_t acc = (f32x16_t)0.0f;
#pragma unroll
    for (int kb = 0; kb < 16; ++kb) {
      f16x8 bh = *(const f16x8*)(bt + kb * 512);
      acc = __builtin_amdgcn_mfma_f32_32x32x16_f16(a[kb], bh, acc, 0, 0, 0);
    }

    // ---- branchless top-2 merge (4 VALU/elem: med3, cmp, cndmask, max) ----
    const int col = csplit * 512 + t * 32 + (l & 31);
#pragma unroll
    for (int r = 0; r < 16; ++r) {
      float v = acc[r];
      float nb2 = __builtin_amdgcn_fmed3f(v, b1[r], b2[r]);  // new runner-up
      if (v > b1[r]) i1[r] = col;  // cmp + cndmask
      b1[r] = fmaxf(b1[r], v);
      b2[r] = nb2;
    }
  }

  // ---- final 32-lane top-2 reduce + candidate write ----
#pragma unroll
  for (int r = 0; r < 16; ++r) {
    float v1 = b1[r], v2 = b2[r];
    int vi = i1[r];
#pragma unroll
    for (int m = 1; m < 32; m <<= 1) {
      float o1 = __shfl_xor(v1, m);
      int oi = __shfl_xor(vi, m);
      float o2 = __shfl_xor(v2, m);
      float n2v = fmaxf(fminf(v1, o1), fmaxf(v2, o2));
      if (o1 > v1 || (o1 == v1 && oi < vi)) {
        v1 = o1;
        vi = oi;
      }
      v2 = n2v;
    }
    if ((l & 31) == 0) {
      int row = rowgrp * 128 + w * 32 + (r & 3) + 8 * (r >> 2) + 4 * (l >> 5);
      cand1[(size_t)row * CSPLIT + csplit] =
          ((unsigned long long)ford(v1) << 32) |
          (unsigned long long)(unsigned int)(NEMB - 1 - vi);
      cand2[(size_t)row * CSPLIT + csplit] = ford(v2);
    }
  }
}

// ---------------------------------------------------------------------------
// Per-row: merge CSPLIT slots -> winner + runner-up -> margin; flag tight rows.
// ---------------------------------------------------------------------------
__global__ __launch_bounds__(256) void finalize1(
    const unsigned long long* __restrict__ cand1,
    const unsigned int* __restrict__ cand2, int* __restrict__ idxi,
    unsigned int* __restrict__ flags, unsigned int* __restrict__ flag_count,
    unsigned int* __restrict__ flag_list) {
  int row = blockIdx.x * 256 + threadIdx.x;
  unsigned long long best = 0;
  unsigned int second = 0;
  int bslot = 0;
#pragma unroll
  for (int s = 0; s < CSPLIT; ++s) {
    unsigned long long v = cand1[(size_t)row * CSPLIT + s];
    unsigned int vs = (unsigned int)(v >> 32);
    if (v > best) {
      second = (unsigned int)(best >> 32);
      best = v;
      bslot = s;
    } else if (vs > second) {
      second = vs;
    }
  }
  unsigned int r2 = cand2[(size_t)row * CSPLIT + bslot];
  if (r2 > second) second = r2;
  float s1 = funord((unsigned int)(best >> 32));
  float s2 = funord(second);
  int idx = NEMB - 1 - (int)(best & 0xFFFFFFFFull);
  idxi[row] = idx;
  unsigned int fl = ((s1 - s2) < TAU) ? 1u : 0u;
  flags[row] = fl;
  if (fl) {
    unsigned int p = atomicAdd(flag_count, 1u);
    flag_list[p] = row;
  }
}

// ---------------------------------------------------------------------------
// Exact fp32 rescore of flagged rows. Block owns 32 codes IN REGISTERS
// (8 float4/thread), z row staged in LDS with part-staggered pitch-36 layout
// (conflict-free b128 reads). 2 rows per iteration, in-wave shuffle reduce,
// one packed atomicMax per row. Thread map: code = w*8+(l&7), part p = l>>3.
// Row-parallel grid: blockIdx.y = rc; block handles flag pairs
// f = 2*rc, 2*rc + 2*RESC_R, ...
// ---------------------------------------------------------------------------
__global__ __launch_bounds__(256) void rescore(
    const float* __restrict__ z, const float* __restrict__ emb,
    const float* __restrict__ inv_norm,
    const unsigned int* __restrict__ flag_list,
    const unsigned int* __restrict__ flag_count,
    unsigned long long* __restrict__ packed_rescore) {
  __shared__ float z_s[2][292];  // [p*36 + j] staggered layout (8*36=288)
  __shared__ unsigned long long red[64];
  const int tid = threadIdx.x;
  const int l = tid & 63;
  const int w = tid >> 6;
  const int cl = l & 7;
  const int p = l >> 3;
  const int code = w * 8 + cl;  // 0..31
  const int cbase = blockIdx.x * 32;
  const unsigned int rc = blockIdx.y;  // row-chunk 0..RESC_R-1

  unsigned int cnt = *flag_count;
  if (2 * rc >= cnt) return;  // whole block: no rows for this chunk

  float4 e4[8];
  const float* ebase = emb + (size_t)(cbase + code) * 256 + p * 32;
#pragma unroll
  for (int j = 0; j < 8; ++j) e4[j] = *(const float4*)&ebase[4 * j];
  const float inv = inv_norm[cbase + code];
  const unsigned int lowbits = (unsigned int)(NEMB - 1 - (cbase + code));

  for (unsigned int f = 2 * rc; f < cnt; f += 2 * RESC_R) {
    int row0 = (int)flag_list[f];
    int row1 = (f + 1 < cnt) ? (int)flag_list[f + 1] : row0;
    __syncthreads();
    if (tid < 128) {
      int half = tid >> 6, t = tid & 63;
      int k0 = t * 4;                       // element index 0..252
      int addr = k0 + 4 * (k0 >> 5);        // staggered address
      const float* zp = z + (size_t)(half ? row1 : row0) * 256 + k0;
      *(float4*)&z_s[half][addr] = *(const float4*)zp;
    }
    __syncthreads();
    float a0 = 0.f, a1 = 0.f;
#pragma unroll
    for (int j = 0; j < 8; ++j) {
      float4 z0 = *(const float4*)&z_s[0][p * 36 + 4 * j];
      float4 z1 = *(const float4*)&z_s[1][p * 36 + 4 * j];
      a0 += e4[j].x * z0.x + e4[j].y * z0.y + e4[j].z * z0.z + e4[j].w * z0.w;
      a1 += e4[j].x * z1.x + e4[j].y * z1.y + e4[j].z * z1.z + e4[j].w * z1.w;
    }
#pragma unroll
    for (int m = 8; m < 64; m <<= 1) {
      a0 += __shfl_xor(a0, m);
      a1 += __shfl_xor(a1, m);
    }
    if (l < 8)
      red[w * 8 + cl] = ((unsigned long long)ford(a0 * inv) << 32) | lowbits;
    else if (l < 16)
      red[32 + w * 8 + cl] = ((unsigned long long)ford(a1 * inv) << 32) | lowbits;
    __syncthreads();
    if (w == 0) {
      unsigned long long v = red[l];
#pragma unroll
      for (int m = 1; m < 32; m <<= 1) {
        unsigned long long o = __shfl_xor(v, m);
        if (o > v) v = o;
      }
      if (l == 0) atomicMax(&packed_rescore[row0], v);
      if (l == 32) atomicMax(&packed_rescore[row1], v);
    }
  }
}

// ---------------------------------------------------------------------------
// Final idx (float) + z_q gather + (optional) zq hi/lo fragment split.
// Block = 32 rows.
// ---------------------------------------------------------------------------
__global__ __launch_bounds__(256) void gather_split(
    const int* __restrict__ idxi, const unsigned int* __restrict__ flags,
    const unsigned long long* __restrict__ packed_rescore,
    const float* __restrict__ emb, float* __restrict__ zq,
    float* __restrict__ idx_out, _Float16* __restrict__ zqfrag,
    size_t lo_off, int use_frag) {
  __shared__ float zrow[32][260];
  __shared__ int idxs[32];
  const int tid = threadIdx.x;
  const int tile = blockIdx.x;
  if (tid < 32) {
    int row = tile * 32 + tid;
    int idx = idxi[row];
    if (flags[row]) idx = NEMB - 1 - (int)(packed_rescore[row] & 0xFFFFFFFFull);
    idxs[tid] = idx;
    idx_out[row] = (float)idx;
  }
  __syncthreads();
#pragma unroll
  for (int t = 0; t < 8; ++t) {
    int flat = t * 256 + tid;
    int r = flat >> 6, c4 = flat & 63;
    float4 v = *(const float4*)&emb[(size_t)idxs[r] * 256 + 4 * c4];
    *(float4*)&zrow[r][4 * c4] = v;
    *(float4*)&zq[(size_t)(tile * 32 + r) * 256 + 4 * c4] = v;
  }
  if (use_frag) {
    __syncthreads();
#pragma unroll
    for (int t = 0; t < 4; ++t) {
      int flat = t * 256 + tid;  // 16 frag blocks x 64 lanes
      int fb = flat >> 6, fl = flat & 63;
      int r = fl & 31, k0 = fb * 16 + (fl >> 5) * 8;
      float4 v0 = *(const float4*)&zrow[r][k0];
      float4 v1 = *(const float4*)&zrow[r][k0 + 4];
      float vv[8] = {v0.x, v0.y, v0.z, v0.w, v1.x, v1.y, v1.z, v1.w};
      f16x8 hv, lv;
#pragma unroll
      for (int j = 0; j < 8; ++j) {
        _Float16 h = (_Float16)vv[j];
        hv[j] = h;
        lv[j] = (_Float16)(vv[j] - (float)h);
      }
      size_t g = ((size_t)(tile * 16 + fb) * 64 + fl) * 8;
      *(f16x8*)(zqfrag + g) = hv;
      *(f16x8*)(zqfrag + lo_off + g) = lv;
    }
  }
}

// ---------------------------------------------------------------------------
extern "C" void kernel_launch(void* const* d_in, const int* in_sizes, int n_in,
                              void* d_out, int out_size, void* d_ws,
                              size_t ws_size, hipStream_t stream) {
  (void)in_sizes; (void)n_in; (void)out_size;
  const float* x     = (const float*)d_in[0];
  const float* enc_w = (const float*)d_in[1];
  const float* enc_b = (const float*)d_in[2];
  const float* emb   = (const float*)d_in[3];
  const float* dec_w = (const float*)d_in[4];
  const float* dec_b = (const float*)d_in[5];

  float* out     = (float*)d_out;
  float* x_recon = out;                               // 8192*1024
  float* z_out   = x_recon + (size_t)BATCH * IN_DIM;  // 8192*256
  float* zq_out  = z_out + (size_t)BATCH * LAT;       // 8192*256
  float* idx_out = zq_out + (size_t)BATCH * LAT;      // 8192 (as float)

  char* ws = (char*)d_ws;
  float* inv_norm = (float*)ws;                                    // 32 KB
  unsigned int* flags = (unsigned int*)(ws + 32768);               // 32 KB
  int* idxi = (int*)(ws + 65536);                                  // 32 KB
  unsigned int* flag_count = (unsigned int*)(ws + 98304);          // (zeroed)
  unsigned long long* packed_rescore =
      (unsigned long long*)(ws + 98432);                           // 64 KB (zeroed)
  unsigned int* flag_list = (unsigned int*)(ws + 163968);          // 32 KB
  _Float16* wfrag  = (_Float16*)(ws + 1048576);                    // 1 MB hi+lo
  _Float16* dwfrag = (_Float16*)(ws + 2097152);                    // 1 MB hi+lo
  _Float16* efrag  = (_Float16*)(ws + 3145728);                    // 4 MB hi only
  _Float16* zfrag  = (_Float16*)(ws + 7340032);                    // 4 MB hi only
  unsigned long long* cand1 = (unsigned long long*)(ws + 11534336); // 1 MB (16 slots)
  unsigned int* cand2 = (unsigned int*)(ws + 12582912);             // 512 KB
  _Float16* zqfrag = (_Float16*)(ws + 15728640);                   // 8 MB hi+lo
  _Float16* xfrag  = (_Float16*)(ws + 24117248);                   // 32 MB hi+lo

  const bool has_zq = ws_size >= 24117248ull;
  const bool has_x  = ws_size >= 57671680ull;

  hipMemsetAsync(ws + 98304, 0, 128 + 65536, stream);

  emb_norms<<<NEMB / 4, 256, 0, stream>>>(emb, inv_norm);
  split16<<<128, 256, 0, stream>>>(enc_w, (const float*)nullptr, wfrag,
                                   (size_t)LAT * IN_DIM, IN_DIM / 16, 1);
  split16<<<128, 256, 0, stream>>>(dec_w, (const float*)nullptr, dwfrag,
                                   (size_t)IN_DIM * LAT, LAT / 16, 1);
  split16<<<1024, 256, 0, stream>>>(emb, inv_norm, efrag, 0, LAT / 16, 0);

  // encoder: z = x @ enc_w^T + enc_b
  if (has_x) {
    split16<<<4096, 256, 0, stream>>>(x, (const float*)nullptr, xfrag,
                                      (size_t)BATCH * IN_DIM, IN_DIM / 16, 1);
    gemm16_frag<<<dim3(LAT / 64, BATCH / 64), 256, 0, stream>>>(
        xfrag, (size_t)BATCH * IN_DIM, wfrag, (size_t)LAT * IN_DIM, enc_b,
        z_out, LAT, IN_DIM);
  } else {
    gemm16<<<dim3(LAT / 64, BATCH / 64), 256, 0, stream>>>(
        x, wfrag, (size_t)LAT * IN_DIM, enc_b, z_out, BATCH, LAT, IN_DIM);
  }

  // z fragments: hi-only (scorer keeps A in registers, lo-MFMA dropped)
  split16<<<1024, 256, 0, stream>>>(z_out, (const float*)nullptr, zfrag,
                                    (size_t)BATCH * LAT, LAT / 16, 0);

  // fused score + top-2 argmax
  score_mfma<<<dim3(CSPLIT, 64), 256, 0, stream>>>(zfrag, efrag, cand1, cand2);

  finalize1<<<32, 256, 0, stream>>>(cand1, cand2, idxi, flags, flag_count,
                                    flag_list);
  rescore<<<dim3(256, RESC_R), 256, 0, stream>>>(
      z_out, emb, inv_norm, flag_list, flag_count, packed_rescore);

  // idx + z_q gather (+ zq frag split for decoder)
  gather_split<<<BATCH / 32, 256, 0, stream>>>(
      idxi, flags, packed_rescore, emb, zq_out, idx_out,
      has_zq ? zqfrag : (_Float16*)nullptr, (size_t)BATCH * LAT,
      has_zq ? 1 : 0);

  // decoder: x_recon = z_q @ dec_w^T + dec_b
  if (has_zq) {
    gemm16_frag<<<dim3(IN_DIM / 64, BATCH / 64), 256, 0, stream>>>(
        zqfrag, (size_t)BATCH * LAT, dwfrag, (size_t)IN_DIM * LAT, dec_b,
        x_recon, IN_DIM, LAT);
  } else {
    gemm16<<<dim3(IN_DIM / 64, BATCH / 64), 256, 0, stream>>>(
        zq_out, dwfrag, (size_t)IN_DIM * LAT, dec_b, x_recon, BATCH, IN_DIM,
        LAT);
  }
}

// Round 8
// 261.797 us; speedup vs baseline: 1.2365x; 1.2365x over previous
//
#include <hip/hip_runtime.h>
#include <math.h>

// Problem constants
#define BATCH   8192
#define IN_DIM  1024
#define LAT     256
#define NEMB    8192

// flag margin; score err sigma ~3.2e-4 (fp16 rounding of BOTH z-hi and e-hat),
// TAU ~ 10 sigma. Flagged rows get exact fp32 rescore.
#define TAU 3.5e-3f

// rescore row-parallelism (grid.y); blocks stride the flag list by 2*RESC_R
#define RESC_R 16

// scorer column splits (grid.x); each handles NEMB/CSPLIT codes
#define CSPLIT 16

typedef _Float16 f16x8 __attribute__((ext_vector_type(8)));
typedef _Float16 f16x4 __attribute__((ext_vector_type(4)));
typedef float f32x16_t __attribute__((ext_vector_type(16)));

typedef __attribute__((address_space(1))) const unsigned int gu32_t;
typedef __attribute__((address_space(3))) unsigned int lu32_t;

// order-preserving float<->u32 transform
__device__ __forceinline__ unsigned int ford(float x) {
  unsigned int u = __float_as_uint(x);
  return (u & 0x80000000u) ? ~u : (u | 0x80000000u);
}
__device__ __forceinline__ float funord(unsigned int t) {
  unsigned int u = (t & 0x80000000u) ? (t & 0x7FFFFFFFu) : ~t;
  return __uint_as_float(u);
}

// ---------------------------------------------------------------------------
// FUSED: per-code inverse norms + scaled fp16-hi fragment split of emb.
// One block = 32 emb rows (one frag tile). Replaces emb_norms + split16(emb).
// ---------------------------------------------------------------------------
__global__ __launch_bounds__(256) void emb_prep(
    const float* __restrict__ emb, float* __restrict__ inv_norm,
    _Float16* __restrict__ efrag) {
  __shared__ float s_inv[32];
  const int tid = threadIdx.x;
  const int l = tid & 63;
  const int w = tid >> 6;
  const int tile = blockIdx.x;  // 0..255

  // norms: 8 threads per row, 32 elems each, 8-lane shfl reduce
  {
    int row = tid >> 3, part = tid & 7;
    const float* p = emb + (size_t)(tile * 32 + row) * 256 + part * 32;
    float s = 0.f;
#pragma unroll
    for (int j = 0; j < 8; ++j) {
      float4 v = *(const float4*)&p[4 * j];
      s += v.x * v.x + v.y * v.y + v.z * v.z + v.w * v.w;
    }
    s += __shfl_xor(s, 1);
    s += __shfl_xor(s, 2);
    s += __shfl_xor(s, 4);
    if (part == 0) {
      float iv = 1.0f / sqrtf(s);
      s_inv[row] = iv;
      inv_norm[tile * 32 + row] = iv;
    }
  }
  __syncthreads();

  // frag split (hi only), 4 kb-blocks per wave
#pragma unroll
  for (int q = 0; q < 4; ++q) {
    int kb = w * 4 + q;
    int row = l & 31;
    int k = kb * 16 + (l >> 5) * 8;
    const float* p = emb + (size_t)(tile * 32 + row) * 256 + k;
    float sc = s_inv[row];
    f16x8 h;
#pragma unroll
    for (int j = 0; j < 8; ++j) h[j] = (_Float16)(p[j] * sc);
    size_t o = ((size_t)(tile * 16 + kb) * 64 + l) * 8;
    *(f16x8*)(efrag + o) = h;
  }
}

// ---------------------------------------------------------------------------
// Split fp32 [R x K] into fp16 hi (+ optional lo) in MFMA-32x32x16 fragment
// order: frag g=(tile,kb): lane l -> elem [tile*32+(l&31)][kb*16+(l>>5)*8+j]
// stored at dst[(g*64+l)*8 + j]; lo at dst + lo_off (= R*K) if write_lo.
// ---------------------------------------------------------------------------
__device__ __forceinline__ void split_body(
    const float* __restrict__ src, _Float16* __restrict__ dst, size_t lo_off,
    int KD, int write_lo, int gw, int l) {
  int tile = gw / KD, kb = gw % KD;
  int row = tile * 32 + (l & 31);
  int k = kb * 16 + (l >> 5) * 8;
  const float* p = src + (size_t)row * (KD * 16) + k;
  f16x8 h, lo;
#pragma unroll
  for (int j = 0; j < 8; ++j) {
    float v = p[j];
    _Float16 hh = (_Float16)v;
    h[j] = hh;
    lo[j] = (_Float16)(v - (float)hh);
  }
  size_t o = ((size_t)gw * 64 + l) * 8;
  *(f16x8*)(dst + o) = h;
  if (write_lo) *(f16x8*)(dst + lo_off + o) = lo;
}

__global__ __launch_bounds__(256) void split16(
    const float* __restrict__ src, _Float16* __restrict__ dst, size_t lo_off,
    int KD, int write_lo) {
  int gw = (blockIdx.x * 256 + threadIdx.x) >> 6;
  split_body(src, dst, lo_off, KD, write_lo, gw, threadIdx.x & 63);
}

// Both weight splits in one launch (enc_w: 128 blocks, dec_w: 128 blocks).
__global__ __launch_bounds__(256) void split_weights(
    const float* __restrict__ enc_w, _Float16* __restrict__ wfrag,
    const float* __restrict__ dec_w, _Float16* __restrict__ dwfrag) {
  int b = blockIdx.x;
  int l = threadIdx.x & 63;
  if (b < 128) {
    int gw = (b * 256 + threadIdx.x) >> 6;
    split_body(enc_w, wfrag, (size_t)LAT * IN_DIM, IN_DIM / 16, 1, gw, l);
  } else {
    int gw = ((b - 128) * 256 + threadIdx.x) >> 6;
    split_body(dec_w, dwfrag, (size_t)IN_DIM * LAT, LAT / 16, 1, gw, l);
  }
}

// ---------------------------------------------------------------------------
// Split-fp16 MFMA GEMM, BOTH operands pre-split in fragment order.
// C[M][N] = A@B^T + bias. Block 64x64, 4 waves (mt=w&1, nt=w>>1), K-slice 64.
// All staging via global_load_lds width=16. 3 MFMAs per k-step.
// ---------------------------------------------------------------------------
__global__ __launch_bounds__(256) void gemm16_frag(
    const _Float16* __restrict__ Afrag, size_t a_lo_off,
    const _Float16* __restrict__ Bfrag, size_t b_lo_off,
    const float* __restrict__ bias, float* __restrict__ C, int N, int K) {
  __shared__ char lds[32768];  // A chunks [0,16K): (mt*8+prec*4+ks); B at 16K
  const int tid = threadIdx.x;
  const int l = tid & 63;
  const int w = tid >> 6;
  const int mt = w & 1, nt = w >> 1;
  const int rb = blockIdx.y * 64, cb = blockIdx.x * 64;
  const int KD = K >> 4;

  f32x16_t acc = (f32x16_t)0.0f;

  for (int s = 0; s < (K >> 6); ++s) {
#pragma unroll
    for (int i = 0; i < 8; ++i) {
      int c = i * 4 + w;  // 0..31
      int isB = c >> 4;
      int cc = c & 15;
      int t32 = cc >> 3, prec = (cc >> 2) & 1, ks = cc & 3;
      int tile = ((isB ? cb : rb) >> 5) + t32;
      int kb = s * 4 + ks;
      const _Float16* base = isB ? Bfrag : Afrag;
      size_t lo = isB ? b_lo_off : a_lo_off;
      const _Float16* src =
          base + (size_t)prec * lo + ((size_t)(tile * KD + kb) * 64 + l) * 8;
      __builtin_amdgcn_global_load_lds((gu32_t*)src,
                                       (lu32_t*)(lds + (c << 10) + l * 16),
                                       16, 0, 0);
    }
    __syncthreads();
#pragma unroll
    for (int ks = 0; ks < 4; ++ks) {
      f16x8 ah = *(const f16x8*)(lds + ((mt * 8 + ks) << 10) + l * 16);
      f16x8 al = *(const f16x8*)(lds + ((mt * 8 + 4 + ks) << 10) + l * 16);
      f16x8 bh = *(const f16x8*)(lds + 16384 + ((nt * 8 + ks) << 10) + l * 16);
      f16x8 bl = *(const f16x8*)(lds + 16384 + ((nt * 8 + 4 + ks) << 10) + l * 16);
      acc = __builtin_amdgcn_mfma_f32_32x32x16_f16(ah, bh, acc, 0, 0, 0);
      acc = __builtin_amdgcn_mfma_f32_32x32x16_f16(ah, bl, acc, 0, 0, 0);
      acc = __builtin_amdgcn_mfma_f32_32x32x16_f16(al, bh, acc, 0, 0, 0);
    }
    __syncthreads();
  }

  int col = cb + nt * 32 + (l & 31);
  float bv = bias[col];
#pragma unroll
  for (int r = 0; r < 16; ++r) {
    int row = rb + mt * 32 + (r & 3) + 8 * (r >> 2) + 4 * (l >> 5);
    C[(size_t)row * N + col] = acc[r] + bv;
  }
}

// ---------------------------------------------------------------------------
// Fallback GEMM (A fp32, split to fp16 hi/lo in-kernel).
// ---------------------------------------------------------------------------
__global__ __launch_bounds__(256) void gemm16(
    const float* __restrict__ A, const _Float16* __restrict__ Bfrag,
    size_t b_lo_off, const float* __restrict__ bias, float* __restrict__ C,
    int M, int N, int K) {
  __shared__ char lds[32768];
  const int tid = threadIdx.x;
  const int l = tid & 63;
  const int w = tid >> 6;
  const int mt = w & 1, nt = w >> 1;
  const int rb = blockIdx.y * 64, cb = blockIdx.x * 64;
  const int KD = K >> 4;

  f32x16_t acc = (f32x16_t)0.0f;

  for (int s = 0; s < (K >> 6); ++s) {
#pragma unroll
    for (int i = 0; i < 4; ++i) {
      int c = i * 4 + w;  // 0..15: ((bnt*2+prec)*4+ks)
      int bnt = c >> 3, prec = (c >> 2) & 1, ks = c & 3;
      int tile = (cb >> 5) + bnt, ksg = s * 4 + ks;
      const _Float16* src = Bfrag + (size_t)prec * b_lo_off +
                            ((size_t)(tile * KD + ksg) * 64 + l) * 8;
      __builtin_amdgcn_global_load_lds((gu32_t*)src,
                                       (lu32_t*)(lds + 16384 + (c << 10) + l * 16),
                                       16, 0, 0);
    }
#pragma unroll
    for (int t = 0; t < 4; ++t) {
      int flat = t * 256 + tid;
      int r = flat >> 4, c4 = flat & 15;
      float4 v = *(const float4*)&A[(size_t)(rb + r) * K + s * 64 + 4 * c4];
      int kk = 4 * c4;
      int ks = kk >> 4, j = kk & 7;
      int lane2 = (r & 31) + 32 * ((kk >> 3) & 1);
      int mtt = r >> 5;
      f16x4 hv, lv;
      float vv[4] = {v.x, v.y, v.z, v.w};
#pragma unroll
      for (int e = 0; e < 4; ++e) {
        _Float16 h = (_Float16)vv[e];
        hv[e] = h;
        lv[e] = (_Float16)(vv[e] - (float)h);
      }
      int base = ((mtt * 8 + ks) << 10) + lane2 * 16 + j * 2;
      *(f16x4*)(lds + base) = hv;
      *(f16x4*)(lds + base + 4096) = lv;
    }
    __syncthreads();
#pragma unroll
    for (int ks = 0; ks < 4; ++ks) {
      f16x8 ah = *(const f16x8*)(lds + ((mt * 8 + ks) << 10) + l * 16);
      f16x8 al = *(const f16x8*)(lds + ((mt * 8 + 4 + ks) << 10) + l * 16);
      f16x8 bh = *(const f16x8*)(lds + 16384 + ((nt * 8 + ks) << 10) + l * 16);
      f16x8 bl = *(const f16x8*)(lds + 16384 + ((nt * 8 + 4 + ks) << 10) + l * 16);
      acc = __builtin_amdgcn_mfma_f32_32x32x16_f16(ah, bh, acc, 0, 0, 0);
      acc = __builtin_amdgcn_mfma_f32_32x32x16_f16(ah, bl, acc, 0, 0, 0);
      acc = __builtin_amdgcn_mfma_f32_32x32x16_f16(al, bh, acc, 0, 0, 0);
    }
    __syncthreads();
  }

  int col = cb + nt * 32 + (l & 31);
  float bv = bias[col];
#pragma unroll
  for (int r = 0; r < 16; ++r) {
    int row = rb + mt * 32 + (r & 3) + 8 * (r >> 2) + 4 * (l >> 5);
    C[(size_t)row * N + col] = acc[r] + bv;
  }
}

// ---------------------------------------------------------------------------
// FUSED decoder: x_recon = z_q @ dec_w^T + dec_b, with z_q gathered DIRECTLY
// from emb by final idx (resolved in prologue) and split hi/lo in-kernel
// (gemm16 pattern, K=256). Replaces gather_split + zqfrag round-trip
// (16 MB write + 128 MB read) with L2-hot emb row gathers.
// Col-block 0 also writes zq_out (fp32 gathered rows) and idx_out.
// ---------------------------------------------------------------------------
__global__ __launch_bounds__(256) void gemm16_dec(
    const int* __restrict__ idxi, const unsigned int* __restrict__ flags,
    const unsigned long long* __restrict__ packed_rescore,
    const float* __restrict__ emb, const _Float16* __restrict__ Bfrag,
    size_t b_lo_off, const float* __restrict__ bias, float* __restrict__ C,
    float* __restrict__ zq, float* __restrict__ idx_out) {
  __shared__ char lds[32768];
  __shared__ int idxs[64];
  const int tid = threadIdx.x;
  const int l = tid & 63;
  const int w = tid >> 6;
  const int mt = w & 1, nt = w >> 1;
  const int rb = blockIdx.y * 64, cb = blockIdx.x * 64;
  const int KD = 16;  // K = 256

  if (tid < 64) {
    int row = rb + tid;
    int idx = idxi[row];
    if (flags[row]) idx = NEMB - 1 - (int)(packed_rescore[row] & 0xFFFFFFFFull);
    idxs[tid] = idx;
    if (blockIdx.x == 0) idx_out[row] = (float)idx;
  }
  __syncthreads();

  f32x16_t acc = (f32x16_t)0.0f;

  for (int s = 0; s < 4; ++s) {
#pragma unroll
    for (int i = 0; i < 4; ++i) {
      int c = i * 4 + w;  // 0..15: ((bnt*2+prec)*4+ks)
      int bnt = c >> 3, prec = (c >> 2) & 1, ks = c & 3;
      int tile = (cb >> 5) + bnt, ksg = s * 4 + ks;
      const _Float16* src = Bfrag + (size_t)prec * b_lo_off +
                            ((size_t)(tile * KD + ksg) * 64 + l) * 8;
      __builtin_amdgcn_global_load_lds((gu32_t*)src,
                                       (lu32_t*)(lds + 16384 + (c << 10) + l * 16),
                                       16, 0, 0);
    }
#pragma unroll
    for (int t = 0; t < 4; ++t) {
      int flat = t * 256 + tid;
      int r = flat >> 4, c4 = flat & 15;
      float4 v = *(const float4*)&emb[(size_t)idxs[r] * 256 + s * 64 + 4 * c4];
      if (blockIdx.x == 0)
        *(float4*)&zq[(size_t)(rb + r) * 256 + s * 64 + 4 * c4] = v;
      int kk = 4 * c4;
      int ks = kk >> 4, j = kk & 7;
      int lane2 = (r & 31) + 32 * ((kk >> 3) & 1);
      int mtt = r >> 5;
      f16x4 hv, lv;
      float vv[4] = {v.x, v.y, v.z, v.w};
#pragma unroll
      for (int e = 0; e < 4; ++e) {
        _Float16 h = (_Float16)vv[e];
        hv[e] = h;
        lv[e] = (_Float16)(vv[e] - (float)h);
      }
      int base = ((mtt * 8 + ks) << 10) + lane2 * 16 + j * 2;
      *(f16x4*)(lds + base) = hv;
      *(f16x4*)(lds + base + 4096) = lv;
    }
    __syncthreads();
#pragma unroll
    for (int ks = 0; ks < 4; ++ks) {
      f16x8 ah = *(const f16x8*)(lds + ((mt * 8 + ks) << 10) + l * 16);
      f16x8 al = *(const f16x8*)(lds + ((mt * 8 + 4 + ks) << 10) + l * 16);
      f16x8 bh = *(const f16x8*)(lds + 16384 + ((nt * 8 + ks) << 10) + l * 16);
      f16x8 bl = *(const f16x8*)(lds + 16384 + ((nt * 8 + 4 + ks) << 10) + l * 16);
      acc = __builtin_amdgcn_mfma_f32_32x32x16_f16(ah, bh, acc, 0, 0, 0);
      acc = __builtin_amdgcn_mfma_f32_32x32x16_f16(ah, bl, acc, 0, 0, 0);
      acc = __builtin_amdgcn_mfma_f32_32x32x16_f16(al, bh, acc, 0, 0, 0);
    }
    __syncthreads();
  }

  int col = cb + nt * 32 + (l & 31);
  float bv = bias[col];
#pragma unroll
  for (int r = 0; r < 16; ++r) {
    int row = rb + mt * 32 + (r & 3) + 8 * (r >> 2) + 4 * (l >> 5);
    C[(size_t)row * IN_DIM + col] = acc[r] + bv;
  }
}

// ---------------------------------------------------------------------------
// Scorer (v6, best measured: 67.7us): per-tile phases, double-buffered B,
// ONE barrier per phase {vmcnt(0); s_barrier; stage(p+1); ds_read+MFMA;
// merge}, dual acc chains, branchless med3 merge. See round-5/6 notes.
// v7 lesson: removing LDS loses 4-wave broadcast amplification -> 124us.
// ---------------------------------------------------------------------------
__global__ __launch_bounds__(256) void score_mfma(
    const _Float16* __restrict__ zfrag, const _Float16* __restrict__ efrag,
    unsigned long long* __restrict__ cand1, unsigned int* __restrict__ cand2) {
  __shared__ char lds[32768];  // 2 x 16KB B buffers
  const int tid = threadIdx.x;
  const int l = tid & 63;
  const int w = tid >> 6;
  const int csplit = blockIdx.x;  // 0..15
  const int rowgrp = blockIdx.y;  // 0..63

  // ---- A: this wave's 32 rows, full K=256, hi-only, in registers ----
  f16x8 a[16];
  {
    const _Float16* ab =
        zfrag + (((size_t)(rowgrp * 4 + w) * 16) * 64 + l) * 8;
#pragma unroll
    for (int kf = 0; kf < 16; ++kf)
      a[kf] = *(const f16x8*)(ab + (size_t)kf * 512);
  }

  float b1[16], b2[16];
  int i1[16];
#pragma unroll
  for (int r = 0; r < 16; ++r) {
    b1[r] = -INFINITY;
    b2[r] = -INFINITY;
    i1[r] = 0;
  }

  // efrag: tile-major, 16 KB per tile (16 frags x 1KB). Block covers tiles
  // csplit*16 .. +15 (512 cols). Stage phase p = tile p: linear tid*16 copy.
  const char* esrc = (const char*)efrag + (size_t)csplit * 262144 + tid * 16;
  char* ldst = lds + tid * 16;        // stage dst (wave-uniform + lane*16)
  const char* ldsr = lds + l * 16;    // ds_read base

  // prologue: stage tile 0 into buf0
#pragma unroll
  for (int i = 0; i < 4; ++i)
    __builtin_amdgcn_global_load_lds((gu32_t*)(esrc + i * 4096),
                                     (lu32_t*)(ldst + i * 4096), 16, 0, 0);

#pragma unroll 1
  for (int p = 0; p < 16; ++p) {
    // own stage(p) loads landed (issued a full phase ago -> near-free wait)
    asm volatile("s_waitcnt vmcnt(0)" ::: "memory");
    // all waves: stage(p) landed AND reads of buf[(p-1)&1] done
    __builtin_amdgcn_s_barrier();
    __builtin_amdgcn_sched_barrier(0);  // nothing moves above the barrier

    // ---- stage next tile into the buffer freed at the barrier ----
    if (p < 15) {
      const char* sb = esrc + (size_t)(p + 1) * 16384;
      char* db = ldst + ((p + 1) & 1) * 16384;
#pragma unroll
      for (int i = 0; i < 4; ++i)
        __builtin_amdgcn_global_load_lds((gu32_t*)(sb + i * 4096),
                                         (lu32_t*)(db + i * 4096), 16, 0, 0);
    }

    // ---- compute tile p: dual chains to halve MFMA dependency latency ----
    const char* bb = ldsr + (p & 1) * 16384;
    f32x16_t acc0 = (f32x16_t)0.0f;
    f32x16_t acc1 = (f32x16_t)0.0f;
#pragma unroll
    for (int kb = 0; kb < 16; kb += 2) {
      f16x8 bh0 = *(const f16x8*)(bb + (kb << 10));
      f16x8 bh1 = *(const f16x8*)(bb + ((kb + 1) << 10));
      acc0 = __builtin_amdgcn_mfma_f32_32x32x16_f16(a[kb], bh0, acc0, 0, 0, 0);
      acc1 = __builtin_amdgcn_mfma_f32_32x32x16_f16(a[kb + 1], bh1, acc1, 0, 0, 0);
    }

    // ---- branchless top-2 merge (4 VALU/elem: med3, cmp, cndmask, max) ----
    const int col = csplit * 512 + p * 32 + (l & 31);
#pragma unroll
    for (int r = 0; r < 16; ++r) {
      float v = acc0[r] + acc1[r];
      float nb2 = __builtin_amdgcn_fmed3f(v, b1[r], b2[r]);  // new runner-up
      if (v > b1[r]) i1[r] = col;  // cmp + cndmask
      b1[r] = fmaxf(b1[r], v);
      b2[r] = nb2;
    }
  }

  // ---- final 32-lane top-2 reduce + candidate write ----
#pragma unroll
  for (int r = 0; r < 16; ++r) {
    float v1 = b1[r], v2 = b2[r];
    int vi = i1[r];
#pragma unroll
    for (int m = 1; m < 32; m <<= 1) {
      float o1 = __shfl_xor(v1, m);
      int oi = __shfl_xor(vi, m);
      float o2 = __shfl_xor(v2, m);
      float n2v = fmaxf(fminf(v1, o1), fmaxf(v2, o2));
      if (o1 > v1 || (o1 == v1 && oi < vi)) {
        v1 = o1;
        vi = oi;
      }
      v2 = n2v;
    }
    if ((l & 31) == 0) {
      int row = rowgrp * 128 + w * 32 + (r & 3) + 8 * (r >> 2) + 4 * (l >> 5);
      cand1[(size_t)row * CSPLIT + csplit] =
          ((unsigned long long)ford(v1) << 32) |
          (unsigned long long)(unsigned int)(NEMB - 1 - vi);
      cand2[(size_t)row * CSPLIT + csplit] = ford(v2);
    }
  }
}

// ---------------------------------------------------------------------------
// Per-row: merge CSPLIT slots -> winner + runner-up -> margin; flag tight rows.
// ---------------------------------------------------------------------------
__global__ __launch_bounds__(256) void finalize1(
    const unsigned long long* __restrict__ cand1,
    const unsigned int* __restrict__ cand2, int* __restrict__ idxi,
    unsigned int* __restrict__ flags, unsigned int* __restrict__ flag_count,
    unsigned int* __restrict__ flag_list) {
  int row = blockIdx.x * 256 + threadIdx.x;
  unsigned long long best = 0;
  unsigned int second = 0;
  int bslot = 0;
#pragma unroll
  for (int s = 0; s < CSPLIT; ++s) {
    unsigned long long v = cand1[(size_t)row * CSPLIT + s];
    unsigned int vs = (unsigned int)(v >> 32);
    if (v > best) {
      second = (unsigned int)(best >> 32);
      best = v;
      bslot = s;
    } else if (vs > second) {
      second = vs;
    }
  }
  unsigned int r2 = cand2[(size_t)row * CSPLIT + bslot];
  if (r2 > second) second = r2;
  float s1 = funord((unsigned int)(best >> 32));
  float s2 = funord(second);
  int idx = NEMB - 1 - (int)(best & 0xFFFFFFFFull);
  idxi[row] = idx;
  unsigned int fl = ((s1 - s2) < TAU) ? 1u : 0u;
  flags[row] = fl;
  if (fl) {
    unsigned int p = atomicAdd(flag_count, 1u);
    flag_list[p] = row;
  }
}

// ---------------------------------------------------------------------------
// Exact fp32 rescore of flagged rows. Block owns 32 codes IN REGISTERS,
// z row staged in LDS (staggered pitch-36, conflict-free b128 reads).
// Row-parallel grid: blockIdx.y = rc; block handles flag pairs
// f = 2*rc, 2*rc + 2*RESC_R, ...
// ---------------------------------------------------------------------------
__global__ __launch_bounds__(256) void rescore(
    const float* __restrict__ z, const float* __restrict__ emb,
    const float* __restrict__ inv_norm,
    const unsigned int* __restrict__ flag_list,
    const unsigned int* __restrict__ flag_count,
    unsigned long long* __restrict__ packed_rescore) {
  __shared__ float z_s[2][292];  // [p*36 + j] staggered layout (8*36=288)
  __shared__ unsigned long long red[64];
  const int tid = threadIdx.x;
  const int l = tid & 63;
  const int w = tid >> 6;
  const int cl = l & 7;
  const int p = l >> 3;
  const int code = w * 8 + cl;  // 0..31
  const int cbase = blockIdx.x * 32;
  const unsigned int rc = blockIdx.y;  // row-chunk 0..RESC_R-1

  unsigned int cnt = *flag_count;
  if (2 * rc >= cnt) return;  // whole block: no rows for this chunk

  float4 e4[8];
  const float* ebase = emb + (size_t)(cbase + code) * 256 + p * 32;
#pragma unroll
  for (int j = 0; j < 8; ++j) e4[j] = *(const float4*)&ebase[4 * j];
  const float inv = inv_norm[cbase + code];
  const unsigned int lowbits = (unsigned int)(NEMB - 1 - (cbase + code));

  for (unsigned int f = 2 * rc; f < cnt; f += 2 * RESC_R) {
    int row0 = (int)flag_list[f];
    int row1 = (f + 1 < cnt) ? (int)flag_list[f + 1] : row0;
    __syncthreads();
    if (tid < 128) {
      int half = tid >> 6, t = tid & 63;
      int k0 = t * 4;                       // element index 0..252
      int addr = k0 + 4 * (k0 >> 5);        // staggered address
      const float* zp = z + (size_t)(half ? row1 : row0) * 256 + k0;
      *(float4*)&z_s[half][addr] = *(const float4*)zp;
    }
    __syncthreads();
    float a0 = 0.f, a1 = 0.f;
#pragma unroll
    for (int j = 0; j < 8; ++j) {
      float4 z0 = *(const float4*)&z_s[0][p * 36 + 4 * j];
      float4 z1 = *(const float4*)&z_s[1][p * 36 + 4 * j];
      a0 += e4[j].x * z0.x + e4[j].y * z0.y + e4[j].z * z0.z + e4[j].w * z0.w;
      a1 += e4[j].x * z1.x + e4[j].y * z1.y + e4[j].z * z1.z + e4[j].w * z1.w;
    }
#pragma unroll
    for (int m = 8; m < 64; m <<= 1) {
      a0 += __shfl_xor(a0, m);
      a1 += __shfl_xor(a1, m);
    }
    if (l < 8)
      red[w * 8 + cl] = ((unsigned long long)ford(a0 * inv) << 32) | lowbits;
    else if (l < 16)
      red[32 + w * 8 + cl] = ((unsigned long long)ford(a1 * inv) << 32) | lowbits;
    __syncthreads();
    if (w == 0) {
      unsigned long long v = red[l];
#pragma unroll
      for (int m = 1; m < 32; m <<= 1) {
        unsigned long long o = __shfl_xor(v, m);
        if (o > v) v = o;
      }
      if (l == 0) atomicMax(&packed_rescore[row0], v);
      if (l == 32) atomicMax(&packed_rescore[row1], v);
    }
  }
}

// ---------------------------------------------------------------------------
extern "C" void kernel_launch(void* const* d_in, const int* in_sizes, int n_in,
                              void* d_out, int out_size, void* d_ws,
                              size_t ws_size, hipStream_t stream) {
  (void)in_sizes; (void)n_in; (void)out_size;
  const float* x     = (const float*)d_in[0];
  const float* enc_w = (const float*)d_in[1];
  const float* enc_b = (const float*)d_in[2];
  const float* emb   = (const float*)d_in[3];
  const float* dec_w = (const float*)d_in[4];
  const float* dec_b = (const float*)d_in[5];

  float* out     = (float*)d_out;
  float* x_recon = out;                               // 8192*1024
  float* z_out   = x_recon + (size_t)BATCH * IN_DIM;  // 8192*256
  float* zq_out  = z_out + (size_t)BATCH * LAT;       // 8192*256
  float* idx_out = zq_out + (size_t)BATCH * LAT;      // 8192 (as float)

  char* ws = (char*)d_ws;
  float* inv_norm = (float*)ws;                                    // 32 KB
  unsigned int* flags = (unsigned int*)(ws + 32768);               // 32 KB
  int* idxi = (int*)(ws + 65536);                                  // 32 KB
  unsigned int* flag_count = (unsigned int*)(ws + 98304);          // (zeroed)
  unsigned long long* packed_rescore =
      (unsigned long long*)(ws + 98432);                           // 64 KB (zeroed)
  unsigned int* flag_list = (unsigned int*)(ws + 163968);          // 32 KB
  _Float16* wfrag  = (_Float16*)(ws + 1048576);                    // 1 MB hi+lo
  _Float16* dwfrag = (_Float16*)(ws + 2097152);                    // 1 MB hi+lo
  _Float16* efrag  = (_Float16*)(ws + 3145728);                    // 4 MB hi only
  _Float16* zfrag  = (_Float16*)(ws + 7340032);                    // 4 MB hi only
  unsigned long long* cand1 = (unsigned long long*)(ws + 11534336); // 1 MB (16 slots)
  unsigned int* cand2 = (unsigned int*)(ws + 12582912);             // 512 KB
  _Float16* xfrag  = (_Float16*)(ws + 24117248);                   // 32 MB hi+lo

  const bool has_x = ws_size >= 57671680ull;

  hipMemsetAsync(ws + 98304, 0, 128 + 65536, stream);

  // fused emb norms + efrag split; both weight splits in one launch
  emb_prep<<<NEMB / 32, 256, 0, stream>>>(emb, inv_norm, efrag);
  split_weights<<<256, 256, 0, stream>>>(enc_w, wfrag, dec_w, dwfrag);

  // encoder: z = x @ enc_w^T + enc_b
  if (has_x) {
    split16<<<4096, 256, 0, stream>>>(x, xfrag, (size_t)BATCH * IN_DIM,
                                      IN_DIM / 16, 1);
    gemm16_frag<<<dim3(LAT / 64, BATCH / 64), 256, 0, stream>>>(
        xfrag, (size_t)BATCH * IN_DIM, wfrag, (size_t)LAT * IN_DIM, enc_b,
        z_out, LAT, IN_DIM);
  } else {
    gemm16<<<dim3(LAT / 64, BATCH / 64), 256, 0, stream>>>(
        x, wfrag, (size_t)LAT * IN_DIM, enc_b, z_out, BATCH, LAT, IN_DIM);
  }

  // z fragments: hi-only (scorer keeps A in registers)
  split16<<<1024, 256, 0, stream>>>(z_out, zfrag, (size_t)BATCH * LAT,
                                    LAT / 16, 0);

  // fused score + top-2 argmax
  score_mfma<<<dim3(CSPLIT, 64), 256, 0, stream>>>(zfrag, efrag, cand1, cand2);

  finalize1<<<32, 256, 0, stream>>>(cand1, cand2, idxi, flags, flag_count,
                                    flag_list);
  rescore<<<dim3(256, RESC_R), 256, 0, stream>>>(
      z_out, emb, inv_norm, flag_list, flag_count, packed_rescore);

  // fused decoder: gather z_q from emb by final idx + GEMM; writes x_recon,
  // zq_out (cb==0), idx_out (cb==0)
  gemm16_dec<<<dim3(IN_DIM / 64, BATCH / 64), 256, 0, stream>>>(
      idxi, flags, packed_rescore, emb, dwfrag, (size_t)IN_DIM * LAT, dec_b,
      x_recon, zq_out, idx_out);
}